// Round 1
// baseline (11808.219 us; speedup 1.0000x reference)
//
#include <hip/hip_runtime.h>
#include <hip/hip_cooperative_groups.h>

namespace cg = cooperative_groups;

constexpr int B  = 16;
constexpr int T  = 64;
constexpr int L  = 64;
constexpr int H  = 256;
constexpr int H2 = 512;   // 2H (K dim)
constexpr int H4 = 1024;  // 4H (N dim)
constexpr int NBLK = 256; // 4 WGs per cell * up to 64 cells
constexpr int NTHR = 256;

__device__ __forceinline__ float fast_sigmoid(float v) {
  return 1.0f / (1.0f + __expf(-v));
}
__device__ __forceinline__ float fast_tanh(float v) {
  // 1 - 2/(e^{2v}+1); saturates correctly for |v| large (exp->inf or 0)
  return 1.0f - 2.0f / (__expf(2.0f * v) + 1.0f);
}

// Wavefront-parallel stacked LSTM.
// ws layout: cbuf[L*B*H], hbuf0[L*B*H], hbuf1[L*B*H]  (3 MB total, fp32)
// At wavefront w: read h from hbuf[w&1], write to hbuf[(w+1)&1].
// Both h buffers are initialized from init_state so first reads of any layer
// (which happen before that layer's first write) see init values.
__global__ __launch_bounds__(NTHR) void lstm_wave(
    const float* __restrict__ x, const float* __restrict__ init_state,
    const float* __restrict__ W, const float* __restrict__ bias,
    float* __restrict__ out, float* __restrict__ ws) {
  float* cbuf  = ws;
  float* hbuf0 = ws + (size_t)L * B * H;
  float* hbuf1 = ws + (size_t)2 * L * B * H;

  cg::grid_group grid = cg::this_grid();
  const int tid = threadIdx.x;
  const int wg  = blockIdx.x;

  // ---- init states (d_ws is re-poisoned before every call) ----
  for (int idx = wg * NTHR + tid; idx < L * B * H; idx += NBLK * NTHR) {
    int l   = idx >> 12;      // /(B*H) = /4096
    int rem = idx & 4095;
    cbuf[idx] = init_state[l * 2 * B * H + rem];
    float hv  = init_state[l * 2 * B * H + B * H + rem];
    hbuf0[idx] = hv;
    hbuf1[idx] = hv;
  }
  grid.sync();

  __shared__ float smem[B * H2];  // 32 KB: staged [inp(256) || h(256)] per batch row

  const int ci    = wg >> 2;   // cell index on the wavefront
  const int chunk = wg & 3;    // which 64-wide hidden-unit chunk of the cell
  const int g     = tid >> 6;  // gate 0..3 (i,j,f,o)
  const int j     = tid & 63;  // hidden unit within chunk
  const int hu    = chunk * 64 + j;
  const int col   = g * H + hu;  // column in [0,1024)

  for (int w = 0; w < T + L - 1; ++w) {
    const int tmin   = (w > L - 1) ? (w - (L - 1)) : 0;
    const int tmax   = (w < T - 1) ? w : (T - 1);
    const int ncells = tmax - tmin + 1;

    if (ci < ncells) {
      const int t = tmin + ci;
      const int l = w - t;
      const float* hread  = (w & 1) ? hbuf1 : hbuf0;
      float*       hwrite = (w & 1) ? hbuf0 : hbuf1;

      // ---- stage concat(input, own h state) into LDS: smem[b*512 + k] ----
      const float* inp0 = (l == 0) ? (x + (size_t)t * H)
                                   : (hread + (size_t)(l - 1) * B * H);
      const int inp_stride = (l == 0) ? (T * H) : H;
      const float* hst = hread + (size_t)l * B * H;
      for (int u = tid; u < B * H / 4; u += NTHR) {
        int b  = u >> 6;
        int k4 = (u & 63) << 2;
        *(float4*)(smem + b * H2 + k4) =
            *(const float4*)(inp0 + b * inp_stride + k4);
        *(float4*)(smem + b * H2 + H + k4) =
            *(const float4*)(hst + b * H + k4);
      }
      __syncthreads();

      // ---- K loop: z[b][col] = sum_k inp[b][k] * W[k][col] ----
      float acc[B];
#pragma unroll
      for (int b = 0; b < B; ++b) acc[b] = 0.0f;
      const float* wp = W + col;
      for (int k = 0; k < H2; k += 4) {
        float w0 = wp[(k + 0) * H4];
        float w1 = wp[(k + 1) * H4];
        float w2 = wp[(k + 2) * H4];
        float w3 = wp[(k + 3) * H4];
#pragma unroll
        for (int b = 0; b < B; ++b) {
          float4 iv = *(const float4*)(smem + b * H2 + k);  // LDS broadcast
          acc[b] = fmaf(iv.x, w0, acc[b]);
          acc[b] = fmaf(iv.y, w1, acc[b]);
          acc[b] = fmaf(iv.z, w2, acc[b]);
          acc[b] = fmaf(iv.w, w3, acc[b]);
        }
      }
      const float bv = bias[col];
      __syncthreads();  // everyone done reading inp region before z overwrites it

      // ---- exchange z across gates via LDS (pad 17 to dodge bank conflicts) ----
#pragma unroll
      for (int b = 0; b < B; ++b) smem[(g * 64 + j) * 17 + b] = acc[b] + bv;
      __syncthreads();

      // ---- LSTM gate epilogue: 16 b x 64 hu units ----
      for (int u = tid; u < B * 64; u += NTHR) {
        int b   = u >> 6;
        int jj  = u & 63;
        int huu = chunk * 64 + jj;
        float iv = smem[(0 * 64 + jj) * 17 + b];
        float jv = smem[(1 * 64 + jj) * 17 + b];
        float fv = smem[(2 * 64 + jj) * 17 + b];
        float ov = smem[(3 * 64 + jj) * 17 + b];
        size_t sidx = (size_t)l * B * H + (size_t)b * H + huu;
        float c_old = cbuf[sidx];
        float nc = fast_sigmoid(fv + 1.0f) * c_old +
                   fast_sigmoid(iv) * fast_tanh(jv);
        float nh = fast_sigmoid(ov) * fast_tanh(nc);
        cbuf[sidx]   = nc;
        hwrite[sidx] = nh;
        if (l == L - 1) out[(size_t)b * T * H + (size_t)t * H + huu] = nh;
      }
    }
    grid.sync();  // also orders this wave's epilogue reads vs next wave's staging
  }
}

extern "C" void kernel_launch(void* const* d_in, const int* in_sizes, int n_in,
                              void* d_out, int out_size, void* d_ws,
                              size_t ws_size, hipStream_t stream) {
  const float* x          = (const float*)d_in[0];
  const float* init_state = (const float*)d_in[1];
  const float* W          = (const float*)d_in[2];
  const float* bias       = (const float*)d_in[3];
  float* out = (float*)d_out;
  float* ws  = (float*)d_ws;
  void* args[] = {(void*)&x, (void*)&init_state, (void*)&W,
                  (void*)&bias, (void*)&out, (void*)&ws};
  hipLaunchCooperativeKernel((const void*)lstm_wave, dim3(NBLK), dim3(NTHR),
                             args, 0, stream);
}

// Round 3
// 786.463 us; speedup vs baseline: 15.0143x; 15.0143x over previous
//
#include <hip/hip_runtime.h>

typedef _Float16 half8 __attribute__((ext_vector_type(8)));
typedef float f32x4 __attribute__((ext_vector_type(4)));

#define SCOPE __HIP_MEMORY_SCOPE_AGENT

// Problem: B=16, T=64, L=64, H=256. K=2H=512, N=4H=1024.
// ws layout (bytes) -- total ~1.02 MB (round 1 proved ws_size >= 3 MB):
constexpr size_t OFF_FLAGS = 0;       // done[64][64] int (16 KB)
constexpr size_t OFF_H     = 65536;   // Hbuf f16: 2 slots * 64 l * 16 b * 256 u = 1 MB

// h(l,t) lives in slot t&1 (init h(l,-1) in slot 1). Overwrite of h(l,t-2) is
// guarded by the back-pressure wait on flags[l+1][t-2].
__device__ __forceinline__ size_t Hidx(int slot, int l, int b, int u) {
  return (((size_t)slot * 64 + l) * 16 + b) * 256 + u;
}
__device__ __forceinline__ float sigm(float v) { return 1.0f / (1.0f + __expf(-v)); }
__device__ __forceinline__ float tanh_(float v) { return 1.0f - 2.0f / (__expf(2.0f * v) + 1.0f); }

// ---------------- init: zero flags, pack h(-1) -> f16 slot 1 ----------------
__global__ void init_ws(const float* __restrict__ init_state, char* ws) {
  int* flags = (int*)(ws + OFF_FLAGS);
  _Float16* Hp = (_Float16*)(ws + OFF_H);
  const int tid = blockIdx.x * 256 + threadIdx.x;  // 65536 threads
  if (tid < 4096) flags[tid] = 0;
  for (int e = tid; e < 64 * 16 * 256; e += 65536) {
    const int u = e & 255, b = (e >> 8) & 15, l = e >> 12;
    Hp[Hidx(1, l, b, u)] = (_Float16)init_state[((l * 2 + 1) * 16 + b) * 256 + u];
  }
}

__device__ __forceinline__ void spin_ge4(int* p) {
  for (int it = 0; it < 4000000; ++it) {
    if (__hip_atomic_load(p, __ATOMIC_RELAXED, SCOPE) >= 4) return;
    __builtin_amdgcn_s_sleep(1);
  }
}

// ---------------- main: 256 WGs = (layer l = wg>>2, slice r = wg&3) ----------------
// Plain launch; 256 blocks at 1 block/CU are all co-resident by capacity.
__global__ __launch_bounds__(256, 1) void lstm_mfma(
    const float* __restrict__ x, const float* __restrict__ init_state,
    const float* __restrict__ W, const float* __restrict__ bias,
    float* __restrict__ out, char* ws) {
  int* flags = (int*)(ws + OFF_FLAGS);
  unsigned long long* Hp64 = (unsigned long long*)(ws + OFF_H);

  const int tid = threadIdx.x;
  const int wg = blockIdx.x;
  const int l = wg >> 2, r = wg & 3;
  const int wv = tid >> 6, lane = tid & 63;

  __shared__ alignas(16) _Float16 aLds[16 * 64 * 8];  // A-frags: [kb][lane][8], 16 KB
  __shared__ alignas(16) float zLds[16 * 260];        // z transpose, 16.6 KB
  __shared__ unsigned short hLds[16 * 64];            // nh f16 bits, 2 KB

  // ---- W slice -> registers, converting f32->f16 in the prologue.
  // B-frag layout (mfma_f32_16x16x32_f16): lane holds B[k=(lane>>4)*8+jj][n=lane&15].
  // Slice-local col nl = j*4 + g  (j = unit-in-slice, g = gate); global col =
  // g*256 + r*64 + j  -> epilogue finds i,j,f,o in 4 adjacent nl columns.
  half8 wreg[64];  // 4 ntiles * 16 kb = 64 frags * 4 VGPR = 256 VGPR
#pragma unroll
  for (int q = 0; q < 4; ++q) {
    const int nl = (wv * 4 + q) * 16 + (lane & 15);
    const int col = (nl & 3) * 256 + r * 64 + (nl >> 2);
#pragma unroll
    for (int kb = 0; kb < 16; ++kb) {
      const int k0 = kb * 32 + (lane >> 4) * 8;
      const float* src = W + (size_t)k0 * 1024 + col;
      half8 hv;
#pragma unroll
      for (int jj = 0; jj < 8; ++jj) hv[jj] = (_Float16)src[(size_t)jj * 1024];
      wreg[q * 16 + kb] = hv;
    }
  }

  // ---- per-thread epilogue identity: unit hu, batches b4*4+0..3 ----
  const int hu = tid & 63, b4 = tid >> 6;
  const int gu = r * 64 + hu;
  float creg[4];
#pragma unroll
  for (int bi = 0; bi < 4; ++bi)
    creg[bi] = init_state[((l * 2 + 0) * 16 + (b4 * 4 + bi)) * 256 + gu];
  const float bi_ = bias[0 * 256 + gu], bj_ = bias[1 * 256 + gu];
  const float bf_ = bias[2 * 256 + gu], bo_ = bias[3 * 256 + gu];

  for (int t = 0; t < 64; ++t) {
    const int slotCur = t & 1, slotPrev = (t + 1) & 1;

    // ---- waits: producer (l-1,t); own siblings (l,t-1); back-pressure (l+1,t-2) ----
    if (tid == 0) {
      if (l > 0) spin_ge4(&flags[(l - 1) * 64 + t]);
      if (t > 0) spin_ge4(&flags[l * 64 + (t - 1)]);
      if (t >= 2 && l < 63) spin_ge4(&flags[(l + 1) * 64 + (t - 2)]);
    }
    __syncthreads();

    // ---- stage A-frags into LDS: entry e=(kb,ln): A[m=ln&15][k=kb*32+(ln>>4)*8+jj] ----
    // k<256: inp = x (l=0) or h(l-1,t);  k>=256: own h(l,t-1)
#pragma unroll
    for (int i = 0; i < 4; ++i) {
      const int e = i * 256 + tid;
      const int kb = e >> 6, ln = e & 63;
      const int m = ln & 15, k0 = kb * 32 + (ln >> 4) * 8;
      _Float16* dst = &aLds[(size_t)(kb * 64 + ln) * 8];
      if (kb < 8) {
        if (l == 0) {
          const float* xs = x + ((size_t)m * 64 + t) * 256 + k0;
          half8 hv;
#pragma unroll
          for (int jj = 0; jj < 8; ++jj) hv[jj] = (_Float16)xs[jj];
          *(half8*)dst = hv;
        } else {
          const size_t b64 = Hidx(slotCur, l - 1, m, k0) >> 2;
          unsigned long long a0 = __hip_atomic_load(Hp64 + b64, __ATOMIC_RELAXED, SCOPE);
          unsigned long long a1 = __hip_atomic_load(Hp64 + b64 + 1, __ATOMIC_RELAXED, SCOPE);
          ((unsigned long long*)dst)[0] = a0;
          ((unsigned long long*)dst)[1] = a1;
        }
      } else {
        const size_t b64 = Hidx(slotPrev, l, m, k0 - 256) >> 2;
        unsigned long long a0 = __hip_atomic_load(Hp64 + b64, __ATOMIC_RELAXED, SCOPE);
        unsigned long long a1 = __hip_atomic_load(Hp64 + b64 + 1, __ATOMIC_RELAXED, SCOPE);
        ((unsigned long long*)dst)[0] = a0;
        ((unsigned long long*)dst)[1] = a1;
      }
    }
    __syncthreads();

    // ---- GEMM: z[16 x 256slice] = A[16x512] * Wslice[512x256], all-register B ----
    f32x4 acc[4] = {{0.f, 0.f, 0.f, 0.f}, {0.f, 0.f, 0.f, 0.f},
                    {0.f, 0.f, 0.f, 0.f}, {0.f, 0.f, 0.f, 0.f}};
#pragma unroll
    for (int kb = 0; kb < 16; ++kb) {
      half8 a = *(const half8*)&aLds[(kb * 64 + lane) * 8];
#pragma unroll
      for (int q = 0; q < 4; ++q)
        acc[q] = __builtin_amdgcn_mfma_f32_16x16x32_f16(a, wreg[q * 16 + kb], acc[q], 0, 0, 0);
    }

    // ---- z -> LDS transpose (C-layout: n=lane&15, m=(lane>>4)*4+reg) ----
#pragma unroll
    for (int q = 0; q < 4; ++q) {
      const int nl = (wv * 4 + q) * 16 + (lane & 15);
      const int m0 = (lane >> 4) * 4;
#pragma unroll
      for (int rg = 0; rg < 4; ++rg) zLds[(m0 + rg) * 260 + nl] = acc[q][rg];
    }
    __syncthreads();

    // ---- LSTM epilogue: thread handles (hu, 4 batches) ----
#pragma unroll
    for (int bi = 0; bi < 4; ++bi) {
      const int b = b4 * 4 + bi;
      f32x4 zg = *(const f32x4*)&zLds[b * 260 + hu * 4];  // (i,j,f,o)
      const float iv = zg[0] + bi_, jv = zg[1] + bj_;
      const float fv = zg[2] + bf_, ov = zg[3] + bo_;
      const float nc = sigm(fv + 1.0f) * creg[bi] + sigm(iv) * tanh_(jv);
      const float nh = sigm(ov) * tanh_(nc);
      creg[bi] = nc;
      union { _Float16 f; unsigned short s; } cv;
      cv.f = (_Float16)nh;
      hLds[b * 64 + hu] = cv.s;
      if (l == 63) out[((size_t)b * 64 + t) * 256 + gu] = nh;
    }
    __syncthreads();

    // ---- publish h(l,t) slice to the coherent point (slot t&1) ----
    {
      const int b = tid >> 4, u0 = (tid & 15) * 4;
      unsigned long long v = *(unsigned long long*)&hLds[b * 64 + u0];
      __hip_atomic_store(Hp64 + (Hidx(slotCur, l, b, r * 64 + u0) >> 2), v,
                         __ATOMIC_RELAXED, SCOPE);
    }
    __syncthreads();  // barrier drains vmcnt: all h stores complete before flagging
    if (tid == 0)
      __hip_atomic_fetch_add(&flags[l * 64 + t], 1, __ATOMIC_RELEASE, SCOPE);
  }
}

extern "C" void kernel_launch(void* const* d_in, const int* in_sizes, int n_in,
                              void* d_out, int out_size, void* d_ws,
                              size_t ws_size, hipStream_t stream) {
  const float* x          = (const float*)d_in[0];
  const float* init_state = (const float*)d_in[1];
  const float* W          = (const float*)d_in[2];
  const float* bias       = (const float*)d_in[3];
  float* out = (float*)d_out;
  char* ws   = (char*)d_ws;

  init_ws<<<256, 256, 0, stream>>>(init_state, ws);
  lstm_mfma<<<256, 256, 0, stream>>>(x, init_state, W, bias, out, ws);
}